// Round 5
// baseline (573.798 us; speedup 1.0000x reference)
//
#include <hip/hip_runtime.h>

#define N_NODES 20000
#define N_EDGES 320000
#define NPAD    20032
#define BN_EPS  1e-5f
#define NBLK    79          // ceil(20000/256)

using bf16x8 = __attribute__((ext_vector_type(8))) short;
using f32x4  = __attribute__((ext_vector_type(4))) float;

__device__ __forceinline__ float bf2f(ushort u) {
  union { unsigned i; float f; } t; t.i = ((unsigned)u) << 16; return t.f;
}
__device__ __forceinline__ ushort f2bf(float f) {
  unsigned x = __float_as_uint(f);
  return (ushort)((x + 0x7fffu + ((x >> 16) & 1u)) >> 16);   // RNE
}

// ---------- CSR build ----------
__global__ void k_deg(const int* __restrict__ dst, int* __restrict__ deg) {
  int t = blockIdx.x * blockDim.x + threadIdx.x;
  if (t < N_EDGES) { unsigned d = (unsigned)dst[t]; if (d < N_NODES) atomicAdd(&deg[d], 1); }
}

__global__ void k_scanA(const int* __restrict__ deg, int* __restrict__ part,
                        int* __restrict__ bsum) {
  __shared__ int buf[256];
  int i = blockIdx.x * 256 + threadIdx.x;
  int v = (i < N_NODES) ? deg[i] : 0;
  buf[threadIdx.x] = v;
  __syncthreads();
  #pragma unroll
  for (int s = 1; s < 256; s <<= 1) {
    int t = (threadIdx.x >= s) ? buf[threadIdx.x - s] : 0;
    __syncthreads();
    buf[threadIdx.x] += t;
    __syncthreads();
  }
  if (i < N_NODES) part[i] = buf[threadIdx.x];
  if (threadIdx.x == 255) bsum[blockIdx.x] = buf[255];
}

__global__ void k_scanB(int* __restrict__ bsum) {
  __shared__ int buf[128];
  int v = (threadIdx.x < NBLK) ? bsum[threadIdx.x] : 0;
  buf[threadIdx.x] = v;
  __syncthreads();
  #pragma unroll
  for (int s = 1; s < 128; s <<= 1) {
    int t = (threadIdx.x >= s) ? buf[threadIdx.x - s] : 0;
    __syncthreads();
    buf[threadIdx.x] += t;
    __syncthreads();
  }
  if (threadIdx.x < NBLK) bsum[threadIdx.x] = buf[threadIdx.x];
}

__global__ void k_scanC(const int* __restrict__ deg, const int* __restrict__ part,
                        const int* __restrict__ bsum, int* __restrict__ rowptr,
                        float* __restrict__ inv) {
  int i = blockIdx.x * 256 + threadIdx.x;
  if (i >= N_NODES) return;
  int off = blockIdx.x ? bsum[blockIdx.x - 1] : 0;
  rowptr[i + 1] = off + part[i];
  if (i == 0) rowptr[0] = 0;
  inv[i] = 1.0f / (float)max(deg[i], 1);
}

__global__ void k_fill(const int* __restrict__ src, const int* __restrict__ dst,
                       int* __restrict__ cursor, int* __restrict__ col) {
  int e = blockIdx.x * blockDim.x + threadIdx.x;
  if (e >= N_EDGES) return;
  unsigned d = (unsigned)dst[e];
  if (d >= N_NODES) return;
  int p = atomicAdd(&cursor[d], 1);
  col[p] = src[e];
}

// ---------- weights -> bf16 pool ----------
__global__ void k_cvtw(const float* s0, const float* s1, const float* s2,
                       const float* s3, const float* s4, const float* s5,
                       const float* s6, const float* s7, const float* s8,
                       const float* s9, ushort* __restrict__ dst) {
  int t = blockIdx.x * blockDim.x + threadIdx.x;
  int e = t * 4;
  if (e >= 425984) return;
  const float* s; int off;
  if      (e < 16384)  { s = s0; off = e; }
  else if (e < 49152)  { s = s1; off = e - 16384; }
  else if (e < 81920)  { s = s2; off = e - 49152; }
  else if (e < 147456) { s = s3; off = e - 81920; }
  else if (e < 212992) { s = s4; off = e - 147456; }
  else if (e < 278528) { s = s5; off = e - 212992; }
  else if (e < 344064) { s = s6; off = e - 278528; }
  else if (e < 376832) { s = s7; off = e - 344064; }
  else if (e < 409600) { s = s8; off = e - 376832; }
  else                 { s = s9; off = e - 409600; }
  float4 v = *(const float4*)(s + off);
  dst[e + 0] = f2bf(v.x); dst[e + 1] = f2bf(v.y);
  dst[e + 2] = f2bf(v.z); dst[e + 3] = f2bf(v.w);
}

// ---------- gather-mean (bf16 in, fp32 acc, bf16 out): one wave per node ----------
template <int DIM>
__global__ __launch_bounds__(256) void k_gather(
    const ushort* __restrict__ z, const int* __restrict__ rowptr,
    const int* __restrict__ col, const float* __restrict__ inv,
    ushort* __restrict__ mean) {
  int node = blockIdx.x * 4 + (threadIdx.x >> 6);
  if (node >= N_NODES) return;
  int lane = threadIdx.x & 63;
  constexpr int V = DIM / 64;
  float acc[V] = {};
  int r0 = rowptr[node], r1 = rowptr[node + 1];
  for (int j = r0; j < r1; ++j) {
    int s = col[j];
    const ushort* zp = z + (size_t)s * DIM + lane * V;
    if constexpr (V == 4) {
      ushort4 v = *(const ushort4*)zp;
      acc[0] += bf2f(v.x); acc[1] += bf2f(v.y);
      acc[2] += bf2f(v.z); acc[3] += bf2f(v.w);
    } else {
      ushort2 v = *(const ushort2*)zp;
      acc[0] += bf2f(v.x); acc[1] += bf2f(v.y);
    }
  }
  float iv = inv[node];
  ushort* mp = mean + (size_t)node * DIM + lane * V;
  #pragma unroll
  for (int k = 0; k < V; ++k) mp[k] = f2bf(acc[k] * iv);
}

// ---------- one GEMM pass: acc[NF] += A-frag(row) @ W-frag(cols) ----------
template <bool F32, int DIN, int NF>
__device__ __forceinline__ void gemm_pass(const void* __restrict__ A,
                                          const ushort* __restrict__ W,
                                          int arow, int la, int lb, f32x4* acc) {
  #pragma unroll
  for (int k0 = 0; k0 < DIN; k0 += 32) {
    bf16x8 a;
    if constexpr (F32) {
      const float* ap = (const float*)A + (size_t)arow * DIN + k0 + lb * 8;
      float4 u = *(const float4*)ap;
      float4 v = *(const float4*)(ap + 4);
      a[0] = (short)f2bf(u.x); a[1] = (short)f2bf(u.y);
      a[2] = (short)f2bf(u.z); a[3] = (short)f2bf(u.w);
      a[4] = (short)f2bf(v.x); a[5] = (short)f2bf(v.y);
      a[6] = (short)f2bf(v.z); a[7] = (short)f2bf(v.w);
    } else {
      a = *(const bf16x8*)((const ushort*)A + (size_t)arow * DIN + k0 + lb * 8);
    }
    #pragma unroll
    for (int nf = 0; nf < NF; ++nf) {
      bf16x8 b = *(const bf16x8*)(W + (size_t)(nf * 16 + la) * DIN + k0 + lb * 8);
      acc[nf] = __builtin_amdgcn_mfma_f32_16x16x32_bf16(a, b, acc[nf], 0, 0, 0);
    }
  }
}

// ---------- dual GEMM: block = 64 rows x full DOUT; wave = 16 rows x DOUT ----------
template <bool AF32, bool CF32, int DIN, int DOUT, bool DUAL>
__global__ __launch_bounds__(256, 1) void k_gemm(
    const void* __restrict__ A1v, const ushort* __restrict__ W1,
    const void* __restrict__ A2v, const ushort* __restrict__ W2,
    const float* __restrict__ bias, void* __restrict__ Cv, int Mstore)
{
  constexpr int NF = DOUT / 16;
  int lane = threadIdx.x & 63, wid = threadIdx.x >> 6;
  int la = lane & 15, lb = lane >> 4;
  int rowBase = blockIdx.x * 64 + wid * 16;
  int arow = rowBase + la; if (arow >= N_NODES) arow = N_NODES - 1;

  f32x4 acc[NF];
  #pragma unroll
  for (int i = 0; i < NF; ++i) acc[i] = {0.f, 0.f, 0.f, 0.f};

  gemm_pass<AF32, DIN, NF>(A1v, W1, arow, la, lb, acc);
  if constexpr (DUAL) gemm_pass<false, DIN, NF>(A2v, W2, arow, la, lb, acc);

  // C/D layout: col = lane&15, row = (lane>>4)*4 + reg
  #pragma unroll
  for (int nf = 0; nf < NF; ++nf) {
    int col = nf * 16 + la;
    float bv = bias ? bias[col] : 0.0f;
    #pragma unroll
    for (int i = 0; i < 4; ++i) {
      int row = rowBase + lb * 4 + i;
      if (row < Mstore) {
        float o = acc[nf][i] + bv;
        if constexpr (CF32) ((float*)Cv)[(size_t)row * DOUT + col] = o;
        else                ((ushort*)Cv)[(size_t)row * DOUT + col] = f2bf(o);
      }
    }
  }
}

// ---------- BN stats (dim 256, bf16 input) ----------
__global__ void k_stats(const ushort* __restrict__ h, float* __restrict__ stats,
                        int rowsPerBlock) {
  int c = threadIdx.x;
  int r0 = blockIdx.x * rowsPerBlock;
  int r1 = r0 + rowsPerBlock; if (r1 > N_NODES) r1 = N_NODES;
  float s = 0.f, q = 0.f;
  for (int r = r0; r < r1; ++r) {
    float v = bf2f(h[(size_t)r * 256 + c]);
    s += v; q += v * v;
  }
  atomicAdd(&stats[c], s);
  atomicAdd(&stats[256 + c], q);
}

__global__ void k_bnprep(const float* __restrict__ stats, const float* __restrict__ gamma,
                         const float* __restrict__ beta, float* __restrict__ bnp) {
  int c = threadIdx.x;
  float m = stats[c] * (1.0f / N_NODES);
  float var = stats[256 + c] * (1.0f / N_NODES) - m * m;
  float rs = rsqrtf(var + BN_EPS);
  float sc = rs * gamma[c];
  bnp[c] = sc;
  bnp[256 + c] = beta[c] - m * sc;
}

__global__ void k_bnrelu(ushort* __restrict__ h, const float* __restrict__ bnp) {
  int t = blockIdx.x * blockDim.x + threadIdx.x;
  int i = t >> 5;
  if (i >= N_NODES) return;
  int g = t & 31;
  ushort* p = h + (size_t)i * 256 + g * 8;
  bf16x8 v = *(bf16x8*)p;
  #pragma unroll
  for (int j = 0; j < 8; ++j) {
    int c = g * 8 + j;
    float f = bf2f((ushort)v[j]) * bnp[c] + bnp[256 + c];
    v[j] = (short)f2bf(fmaxf(f, 0.0f));
  }
  *(bf16x8*)p = v;
}

extern "C" void kernel_launch(void* const* d_in, const int* in_sizes, int n_in,
                              void* d_out, int out_size, void* d_ws, size_t ws_size,
                              hipStream_t stream) {
  const float* x    = (const float*)d_in[0];
  const int*   ei   = (const int*)d_in[1];
  const float* encW = (const float*)d_in[2];
  const float* encb = (const float*)d_in[3];
  const float* Wl0  = (const float*)d_in[4];
  const float* bl0  = (const float*)d_in[5];
  const float* Wr0  = (const float*)d_in[6];
  const float* Wl1  = (const float*)d_in[7];
  const float* bl1  = (const float*)d_in[8];
  const float* Wr1  = (const float*)d_in[9];
  const float* Wl2  = (const float*)d_in[10];
  const float* bl2  = (const float*)d_in[11];
  const float* Wr2  = (const float*)d_in[12];
  const float* Wl3  = (const float*)d_in[13];
  const float* bl3  = (const float*)d_in[14];
  const float* Wr3  = (const float*)d_in[15];
  const float* g0   = (const float*)d_in[16];
  const float* b0   = (const float*)d_in[17];
  const float* g1   = (const float*)d_in[18];
  const float* b1   = (const float*)d_in[19];
  const float* g2   = (const float*)d_in[20];
  const float* b2   = (const float*)d_in[21];
  const float* decW = (const float*)d_in[22];
  const float* decb = (const float*)d_in[23];

  const int* src = ei;
  const int* dst = ei + N_EDGES;

  char* ws = (char*)d_ws;
  size_t off = 0;
  auto alloc = [&](size_t bytes) { char* p = ws + off; off += (bytes + 255) & ~255ull; return p; };
  ushort* bufA   = (ushort*)alloc((size_t)NPAD * 256 * 2);
  ushort* bufB   = (ushort*)alloc((size_t)NPAD * 256 * 2);
  ushort* mean   = (ushort*)alloc((size_t)NPAD * 256 * 2);
  int*    deg    = (int*)   alloc((size_t)N_NODES * 4);
  int*    part   = (int*)   alloc((size_t)N_NODES * 4);
  int*    bsum   = (int*)   alloc(128 * 4);
  int*    rowptr = (int*)   alloc((size_t)(N_NODES + 1) * 4);
  int*    cursor = (int*)   alloc((size_t)N_NODES * 4);
  int*    colidx = (int*)   alloc((size_t)N_EDGES * 4);
  float*  inv    = (float*) alloc((size_t)N_NODES * 4);
  float*  stats  = (float*) alloc(512 * 4);
  float*  bnp    = (float*) alloc(512 * 4);
  ushort* wpool  = (ushort*)alloc(425984 * 2);

  const ushort* wEnc = wpool;
  const ushort* wL0  = wpool + 16384;
  const ushort* wR0  = wpool + 49152;
  const ushort* wL1  = wpool + 81920;
  const ushort* wR1  = wpool + 147456;
  const ushort* wL2  = wpool + 212992;
  const ushort* wR2  = wpool + 278528;
  const ushort* wL3  = wpool + 344064;
  const ushort* wR3  = wpool + 376832;
  const ushort* wDec = wpool + 409600;

  // ---- CSR build (once; reused by all 4 layers) ----
  hipMemsetAsync(deg, 0, (size_t)N_NODES * 4, stream);
  k_deg<<<(N_EDGES + 255) / 256, 256, 0, stream>>>(dst, deg);
  k_scanA<<<NBLK, 256, 0, stream>>>(deg, part, bsum);
  k_scanB<<<1, 128, 0, stream>>>(bsum);
  k_scanC<<<NBLK, 256, 0, stream>>>(deg, part, bsum, rowptr, inv);
  hipMemcpyAsync(cursor, rowptr, (size_t)N_NODES * 4, hipMemcpyDeviceToDevice, stream);
  k_fill<<<(N_EDGES + 255) / 256, 256, 0, stream>>>(src, dst, cursor, colidx);

  k_cvtw<<<(106496 + 255) / 256, 256, 0, stream>>>(encW, Wl0, Wr0, Wl1, Wr1, Wl2, Wr2,
                                                   Wl3, Wr3, decW, wpool);

  const int GGRID = NPAD / 64;   // 313

  // encoder: bufA = x @ encW^T + encb  (f32 A, bf16 C)
  k_gemm<true, false, 128, 128, false><<<GGRID, 256, 0, stream>>>(
      x, wEnc, nullptr, nullptr, encb, bufA, N_NODES);

  auto bnrelu = [&](ushort* h, const float* ga, const float* be) {
    hipMemsetAsync(stats, 0, 512 * 4, stream);
    k_stats<<<200, 256, 0, stream>>>(h, stats, 100);
    k_bnprep<<<1, 256, 0, stream>>>(stats, ga, be, bnp);
    int total = N_NODES * 32;
    k_bnrelu<<<(total + 255) / 256, 256, 0, stream>>>(h, bnp);
  };

  // SAGE 0: din 128 -> dout 256
  k_gather<128><<<(N_NODES + 3) / 4, 256, 0, stream>>>(bufA, rowptr, colidx, inv, mean);
  k_gemm<false, false, 128, 256, true><<<GGRID, 256, 0, stream>>>(
      mean, wL0, bufA, wR0, bl0, bufB, N_NODES);
  bnrelu(bufB, g0, b0);

  // SAGE 1: 256 -> 256
  k_gather<256><<<(N_NODES + 3) / 4, 256, 0, stream>>>(bufB, rowptr, colidx, inv, mean);
  k_gemm<false, false, 256, 256, true><<<GGRID, 256, 0, stream>>>(
      mean, wL1, bufB, wR1, bl1, bufA, N_NODES);
  bnrelu(bufA, g1, b1);

  // SAGE 2: 256 -> 256
  k_gather<256><<<(N_NODES + 3) / 4, 256, 0, stream>>>(bufA, rowptr, colidx, inv, mean);
  k_gemm<false, false, 256, 256, true><<<GGRID, 256, 0, stream>>>(
      mean, wL2, bufA, wR2, bl2, bufB, N_NODES);
  bnrelu(bufB, g2, b2);

  // SAGE 3: 256 -> 128 (no BN/ReLU)
  k_gather<256><<<(N_NODES + 3) / 4, 256, 0, stream>>>(bufB, rowptr, colidx, inv, mean);
  k_gemm<false, false, 256, 128, true><<<GGRID, 256, 0, stream>>>(
      mean, wL3, bufB, wR3, bl3, bufA, N_NODES);

  // decoder: d_out = bufA @ decW^T + decb  (bf16 A, f32 C)
  k_gemm<false, true, 128, 128, false><<<GGRID, 256, 0, stream>>>(
      bufA, wDec, nullptr, nullptr, decb, (float*)d_out, N_NODES);
}

// Round 6
// 503.364 us; speedup vs baseline: 1.1399x; 1.1399x over previous
//
#include <hip/hip_runtime.h>

#define N_NODES 20000
#define N_EDGES 320000
#define NPAD    20032
#define BN_EPS  1e-5f
#define NBLK    79          // ceil(20000/256)

using bf16x8 = __attribute__((ext_vector_type(8))) short;
using f32x4  = __attribute__((ext_vector_type(4))) float;

__device__ __forceinline__ float bf2f(ushort u) {
  union { unsigned i; float f; } t; t.i = ((unsigned)u) << 16; return t.f;
}
__device__ __forceinline__ ushort f2bf(float f) {
  unsigned x = __float_as_uint(f);
  return (ushort)((x + 0x7fffu + ((x >> 16) & 1u)) >> 16);   // RNE
}

// ---------- CSR build ----------
__global__ void k_deg(const int* __restrict__ dst, int* __restrict__ deg) {
  int t = blockIdx.x * blockDim.x + threadIdx.x;
  if (t < N_EDGES) { unsigned d = (unsigned)dst[t]; if (d < N_NODES) atomicAdd(&deg[d], 1); }
}

__global__ void k_scanA(const int* __restrict__ deg, int* __restrict__ part,
                        int* __restrict__ bsum) {
  __shared__ int buf[256];
  int i = blockIdx.x * 256 + threadIdx.x;
  int v = (i < N_NODES) ? deg[i] : 0;
  buf[threadIdx.x] = v;
  __syncthreads();
  #pragma unroll
  for (int s = 1; s < 256; s <<= 1) {
    int t = (threadIdx.x >= s) ? buf[threadIdx.x - s] : 0;
    __syncthreads();
    buf[threadIdx.x] += t;
    __syncthreads();
  }
  if (i < N_NODES) part[i] = buf[threadIdx.x];
  if (threadIdx.x == 255) bsum[blockIdx.x] = buf[255];
}

__global__ void k_scanB(int* __restrict__ bsum) {
  __shared__ int buf[128];
  int v = (threadIdx.x < NBLK) ? bsum[threadIdx.x] : 0;
  buf[threadIdx.x] = v;
  __syncthreads();
  #pragma unroll
  for (int s = 1; s < 128; s <<= 1) {
    int t = (threadIdx.x >= s) ? buf[threadIdx.x - s] : 0;
    __syncthreads();
    buf[threadIdx.x] += t;
    __syncthreads();
  }
  if (threadIdx.x < NBLK) bsum[threadIdx.x] = buf[threadIdx.x];
}

__global__ void k_scanC(const int* __restrict__ deg, const int* __restrict__ part,
                        const int* __restrict__ bsum, int* __restrict__ rowptr,
                        float* __restrict__ inv) {
  int i = blockIdx.x * 256 + threadIdx.x;
  if (i >= N_NODES) return;
  int off = blockIdx.x ? bsum[blockIdx.x - 1] : 0;
  rowptr[i + 1] = off + part[i];
  if (i == 0) rowptr[0] = 0;
  inv[i] = 1.0f / (float)max(deg[i], 1);
}

__global__ void k_fill(const int* __restrict__ src, const int* __restrict__ dst,
                       int* __restrict__ cursor, int* __restrict__ col) {
  int e = blockIdx.x * blockDim.x + threadIdx.x;
  if (e >= N_EDGES) return;
  unsigned d = (unsigned)dst[e];
  if (d >= N_NODES) return;
  int p = atomicAdd(&cursor[d], 1);
  col[p] = src[e];
}

// ---------- weights -> bf16 pool ----------
__global__ void k_cvtw(const float* s0, const float* s1, const float* s2,
                       const float* s3, const float* s4, const float* s5,
                       const float* s6, const float* s7, const float* s8,
                       const float* s9, ushort* __restrict__ dst) {
  int t = blockIdx.x * blockDim.x + threadIdx.x;
  int e = t * 4;
  if (e >= 425984) return;
  const float* s; int off;
  if      (e < 16384)  { s = s0; off = e; }
  else if (e < 49152)  { s = s1; off = e - 16384; }
  else if (e < 81920)  { s = s2; off = e - 49152; }
  else if (e < 147456) { s = s3; off = e - 81920; }
  else if (e < 212992) { s = s4; off = e - 147456; }
  else if (e < 278528) { s = s5; off = e - 212992; }
  else if (e < 344064) { s = s6; off = e - 278528; }
  else if (e < 376832) { s = s7; off = e - 344064; }
  else if (e < 409600) { s = s8; off = e - 376832; }
  else                 { s = s9; off = e - 409600; }
  float4 v = *(const float4*)(s + off);
  dst[e + 0] = f2bf(v.x); dst[e + 1] = f2bf(v.y);
  dst[e + 2] = f2bf(v.z); dst[e + 3] = f2bf(v.w);
}

// ---------- gather-mean (bf16 in, fp32 acc, bf16 out): one wave per node ----------
template <int DIM>
__global__ __launch_bounds__(256) void k_gather(
    const ushort* __restrict__ z, const int* __restrict__ rowptr,
    const int* __restrict__ col, const float* __restrict__ inv,
    ushort* __restrict__ mean) {
  int node = blockIdx.x * 4 + (threadIdx.x >> 6);
  if (node >= N_NODES) return;
  int lane = threadIdx.x & 63;
  constexpr int V = DIM / 64;
  float acc[V] = {};
  int r0 = rowptr[node], r1 = rowptr[node + 1];
  for (int j = r0; j < r1; ++j) {
    int s = col[j];
    const ushort* zp = z + (size_t)s * DIM + lane * V;
    if constexpr (V == 4) {
      ushort4 v = *(const ushort4*)zp;
      acc[0] += bf2f(v.x); acc[1] += bf2f(v.y);
      acc[2] += bf2f(v.z); acc[3] += bf2f(v.w);
    } else {
      ushort2 v = *(const ushort2*)zp;
      acc[0] += bf2f(v.x); acc[1] += bf2f(v.y);
    }
  }
  float iv = inv[node];
  ushort* mp = mean + (size_t)node * DIM + lane * V;
  #pragma unroll
  for (int k = 0; k < V; ++k) mp[k] = f2bf(acc[k] * iv);
}

// ---------- one fully-unrolled GEMM pass: acc[4] += A-frag(row) @ W-frag(4 col-tiles) ----------
template <bool F32, int DIN>
__device__ __forceinline__ void gemm_pass(const void* __restrict__ A,
                                          const ushort* __restrict__ W,   // pre-offset by colBase
                                          int arow, int la, int lb, f32x4* acc) {
  #pragma unroll
  for (int k0 = 0; k0 < DIN; k0 += 32) {
    bf16x8 a;
    if constexpr (F32) {
      const float* ap = (const float*)A + (size_t)arow * DIN + k0 + lb * 8;
      float4 u = *(const float4*)ap;
      float4 v = *(const float4*)(ap + 4);
      a[0] = (short)f2bf(u.x); a[1] = (short)f2bf(u.y);
      a[2] = (short)f2bf(u.z); a[3] = (short)f2bf(u.w);
      a[4] = (short)f2bf(v.x); a[5] = (short)f2bf(v.y);
      a[6] = (short)f2bf(v.z); a[7] = (short)f2bf(v.w);
    } else {
      a = *(const bf16x8*)((const ushort*)A + (size_t)arow * DIN + k0 + lb * 8);
    }
    #pragma unroll
    for (int nf = 0; nf < 4; ++nf) {
      bf16x8 b = *(const bf16x8*)(W + (size_t)(nf * 16 + la) * DIN + k0 + lb * 8);
      acc[nf] = __builtin_amdgcn_mfma_f32_16x16x32_bf16(a, b, acc[nf], 0, 0, 0);
    }
  }
}

// ---------- dual GEMM: grid (M/64, DOUT/64); block = 64 rows x 64 cols, 4 waves ----------
template <bool AF32, bool CF32, int DIN, int DOUT, bool DUAL>
__global__ __launch_bounds__(256) void k_gemm(
    const void* __restrict__ A1v, const ushort* __restrict__ W1,
    const void* __restrict__ A2v, const ushort* __restrict__ W2,
    const float* __restrict__ bias, void* __restrict__ Cv, int Mstore)
{
  int lane = threadIdx.x & 63, wid = threadIdx.x >> 6;
  int la = lane & 15, lb = lane >> 4;
  int rowBase = blockIdx.x * 64 + wid * 16;
  int colBase = blockIdx.y * 64;
  int arow = rowBase + la; if (arow >= N_NODES) arow = N_NODES - 1;

  f32x4 acc[4];
  #pragma unroll
  for (int i = 0; i < 4; ++i) acc[i] = {0.f, 0.f, 0.f, 0.f};

  gemm_pass<AF32, DIN>(A1v, W1 + (size_t)colBase * DIN, arow, la, lb, acc);
  if constexpr (DUAL)
    gemm_pass<false, DIN>(A2v, W2 + (size_t)colBase * DIN, arow, la, lb, acc);

  // C/D layout: col = lane&15, row = (lane>>4)*4 + reg
  #pragma unroll
  for (int nf = 0; nf < 4; ++nf) {
    int col = colBase + nf * 16 + la;
    float bv = bias ? bias[col] : 0.0f;
    #pragma unroll
    for (int i = 0; i < 4; ++i) {
      int row = rowBase + lb * 4 + i;
      if (row < Mstore) {
        float o = acc[nf][i] + bv;
        if constexpr (CF32) ((float*)Cv)[(size_t)row * DOUT + col] = o;
        else                ((ushort*)Cv)[(size_t)row * DOUT + col] = f2bf(o);
      }
    }
  }
}

// ---------- BN stats (dim 256, bf16 input) ----------
__global__ void k_stats(const ushort* __restrict__ h, float* __restrict__ stats,
                        int rowsPerBlock) {
  int c = threadIdx.x;
  int r0 = blockIdx.x * rowsPerBlock;
  int r1 = r0 + rowsPerBlock; if (r1 > N_NODES) r1 = N_NODES;
  float s = 0.f, q = 0.f;
  for (int r = r0; r < r1; ++r) {
    float v = bf2f(h[(size_t)r * 256 + c]);
    s += v; q += v * v;
  }
  atomicAdd(&stats[c], s);
  atomicAdd(&stats[256 + c], q);
}

__global__ void k_bnprep(const float* __restrict__ stats, const float* __restrict__ gamma,
                         const float* __restrict__ beta, float* __restrict__ bnp) {
  int c = threadIdx.x;
  float m = stats[c] * (1.0f / N_NODES);
  float var = stats[256 + c] * (1.0f / N_NODES) - m * m;
  float rs = rsqrtf(var + BN_EPS);
  float sc = rs * gamma[c];
  bnp[c] = sc;
  bnp[256 + c] = beta[c] - m * sc;
}

__global__ void k_bnrelu(ushort* __restrict__ h, const float* __restrict__ bnp) {
  int t = blockIdx.x * blockDim.x + threadIdx.x;
  int i = t >> 5;
  if (i >= N_NODES) return;
  int g = t & 31;
  ushort* p = h + (size_t)i * 256 + g * 8;
  bf16x8 v = *(bf16x8*)p;
  #pragma unroll
  for (int j = 0; j < 8; ++j) {
    int c = g * 8 + j;
    float f = bf2f((ushort)v[j]) * bnp[c] + bnp[256 + c];
    v[j] = (short)f2bf(fmaxf(f, 0.0f));
  }
  *(bf16x8*)p = v;
}

extern "C" void kernel_launch(void* const* d_in, const int* in_sizes, int n_in,
                              void* d_out, int out_size, void* d_ws, size_t ws_size,
                              hipStream_t stream) {
  const float* x    = (const float*)d_in[0];
  const int*   ei   = (const int*)d_in[1];
  const float* encW = (const float*)d_in[2];
  const float* encb = (const float*)d_in[3];
  const float* Wl0  = (const float*)d_in[4];
  const float* bl0  = (const float*)d_in[5];
  const float* Wr0  = (const float*)d_in[6];
  const float* Wl1  = (const float*)d_in[7];
  const float* bl1  = (const float*)d_in[8];
  const float* Wr1  = (const float*)d_in[9];
  const float* Wl2  = (const float*)d_in[10];
  const float* bl2  = (const float*)d_in[11];
  const float* Wr2  = (const float*)d_in[12];
  const float* Wl3  = (const float*)d_in[13];
  const float* bl3  = (const float*)d_in[14];
  const float* Wr3  = (const float*)d_in[15];
  const float* g0   = (const float*)d_in[16];
  const float* b0   = (const float*)d_in[17];
  const float* g1   = (const float*)d_in[18];
  const float* b1   = (const float*)d_in[19];
  const float* g2   = (const float*)d_in[20];
  const float* b2   = (const float*)d_in[21];
  const float* decW = (const float*)d_in[22];
  const float* decb = (const float*)d_in[23];

  const int* src = ei;
  const int* dst = ei + N_EDGES;

  char* ws = (char*)d_ws;
  size_t off = 0;
  auto alloc = [&](size_t bytes) { char* p = ws + off; off += (bytes + 255) & ~255ull; return p; };
  ushort* bufA   = (ushort*)alloc((size_t)NPAD * 256 * 2);
  ushort* bufB   = (ushort*)alloc((size_t)NPAD * 256 * 2);
  ushort* mean   = (ushort*)alloc((size_t)NPAD * 256 * 2);
  int*    deg    = (int*)   alloc((size_t)N_NODES * 4);
  int*    part   = (int*)   alloc((size_t)N_NODES * 4);
  int*    bsum   = (int*)   alloc(128 * 4);
  int*    rowptr = (int*)   alloc((size_t)(N_NODES + 1) * 4);
  int*    cursor = (int*)   alloc((size_t)N_NODES * 4);
  int*    colidx = (int*)   alloc((size_t)N_EDGES * 4);
  float*  inv    = (float*) alloc((size_t)N_NODES * 4);
  float*  stats  = (float*) alloc(512 * 4);
  float*  bnp    = (float*) alloc(512 * 4);
  ushort* wpool  = (ushort*)alloc(425984 * 2);

  const ushort* wEnc = wpool;
  const ushort* wL0  = wpool + 16384;
  const ushort* wR0  = wpool + 49152;
  const ushort* wL1  = wpool + 81920;
  const ushort* wR1  = wpool + 147456;
  const ushort* wL2  = wpool + 212992;
  const ushort* wR2  = wpool + 278528;
  const ushort* wL3  = wpool + 344064;
  const ushort* wR3  = wpool + 376832;
  const ushort* wDec = wpool + 409600;

  // ---- CSR build (once; reused by all 4 layers) ----
  hipMemsetAsync(deg, 0, (size_t)N_NODES * 4, stream);
  k_deg<<<(N_EDGES + 255) / 256, 256, 0, stream>>>(dst, deg);
  k_scanA<<<NBLK, 256, 0, stream>>>(deg, part, bsum);
  k_scanB<<<1, 128, 0, stream>>>(bsum);
  k_scanC<<<NBLK, 256, 0, stream>>>(deg, part, bsum, rowptr, inv);
  hipMemcpyAsync(cursor, rowptr, (size_t)N_NODES * 4, hipMemcpyDeviceToDevice, stream);
  k_fill<<<(N_EDGES + 255) / 256, 256, 0, stream>>>(src, dst, cursor, colidx);

  k_cvtw<<<(106496 + 255) / 256, 256, 0, stream>>>(encW, Wl0, Wr0, Wl1, Wr1, Wl2, Wr2,
                                                   Wl3, Wr3, decW, wpool);

  const int GGRID = NPAD / 64;   // 313

  // encoder: bufA = x @ encW^T + encb  (f32 A, bf16 C)
  k_gemm<true, false, 128, 128, false><<<dim3(GGRID, 2), 256, 0, stream>>>(
      x, wEnc, nullptr, nullptr, encb, bufA, N_NODES);

  auto bnrelu = [&](ushort* h, const float* ga, const float* be) {
    hipMemsetAsync(stats, 0, 512 * 4, stream);
    k_stats<<<200, 256, 0, stream>>>(h, stats, 100);
    k_bnprep<<<1, 256, 0, stream>>>(stats, ga, be, bnp);
    int total = N_NODES * 32;
    k_bnrelu<<<(total + 255) / 256, 256, 0, stream>>>(h, bnp);
  };

  // SAGE 0: din 128 -> dout 256
  k_gather<128><<<(N_NODES + 3) / 4, 256, 0, stream>>>(bufA, rowptr, colidx, inv, mean);
  k_gemm<false, false, 128, 256, true><<<dim3(GGRID, 4), 256, 0, stream>>>(
      mean, wL0, bufA, wR0, bl0, bufB, N_NODES);
  bnrelu(bufB, g0, b0);

  // SAGE 1: 256 -> 256
  k_gather<256><<<(N_NODES + 3) / 4, 256, 0, stream>>>(bufB, rowptr, colidx, inv, mean);
  k_gemm<false, false, 256, 256, true><<<dim3(GGRID, 4), 256, 0, stream>>>(
      mean, wL1, bufB, wR1, bl1, bufA, N_NODES);
  bnrelu(bufA, g1, b1);

  // SAGE 2: 256 -> 256
  k_gather<256><<<(N_NODES + 3) / 4, 256, 0, stream>>>(bufA, rowptr, colidx, inv, mean);
  k_gemm<false, false, 256, 256, true><<<dim3(GGRID, 4), 256, 0, stream>>>(
      mean, wL2, bufA, wR2, bl2, bufB, N_NODES);
  bnrelu(bufB, g2, b2);

  // SAGE 3: 256 -> 128 (no BN/ReLU)
  k_gather<256><<<(N_NODES + 3) / 4, 256, 0, stream>>>(bufB, rowptr, colidx, inv, mean);
  k_gemm<false, false, 256, 128, true><<<dim3(GGRID, 2), 256, 0, stream>>>(
      mean, wL3, bufB, wR3, bl3, bufA, N_NODES);

  // decoder: d_out = bufA @ decW^T + decb  (bf16 A, f32 C)
  k_gemm<false, true, 128, 128, false><<<dim3(GGRID, 2), 256, 0, stream>>>(
      bufA, wDec, nullptr, nullptr, decb, (float*)d_out, N_NODES);
}

// Round 7
// 318.570 us; speedup vs baseline: 1.8012x; 1.5801x over previous
//
#include <hip/hip_runtime.h>

#define N_NODES 20000
#define N_EDGES 320000
#define NPAD    20032
#define BN_EPS  1e-5f
#define NBLK    79          // ceil(20000/256)

using bf16x8 = __attribute__((ext_vector_type(8))) short;
using f32x4  = __attribute__((ext_vector_type(4))) float;

__device__ __forceinline__ float bf2f(ushort u) {
  union { unsigned i; float f; } t; t.i = ((unsigned)u) << 16; return t.f;
}
__device__ __forceinline__ ushort f2bf(float f) {
  unsigned x = __float_as_uint(f);
  return (ushort)((x + 0x7fffu + ((x >> 16) & 1u)) >> 16);   // RNE
}

// ---------- CSR build ----------
__global__ void k_deg(const int* __restrict__ dst, int* __restrict__ deg) {
  int t = blockIdx.x * blockDim.x + threadIdx.x;
  if (t < N_EDGES) { unsigned d = (unsigned)dst[t]; if (d < N_NODES) atomicAdd(&deg[d], 1); }
}

__global__ void k_scanA(const int* __restrict__ deg, int* __restrict__ part,
                        int* __restrict__ bsum) {
  __shared__ int buf[256];
  int i = blockIdx.x * 256 + threadIdx.x;
  int v = (i < N_NODES) ? deg[i] : 0;
  buf[threadIdx.x] = v;
  __syncthreads();
  #pragma unroll
  for (int s = 1; s < 256; s <<= 1) {
    int t = (threadIdx.x >= s) ? buf[threadIdx.x - s] : 0;
    __syncthreads();
    buf[threadIdx.x] += t;
    __syncthreads();
  }
  if (i < N_NODES) part[i] = buf[threadIdx.x];
  if (threadIdx.x == 255) bsum[blockIdx.x] = buf[255];
}

__global__ void k_scanB(int* __restrict__ bsum) {
  __shared__ int buf[128];
  int v = (threadIdx.x < NBLK) ? bsum[threadIdx.x] : 0;
  buf[threadIdx.x] = v;
  __syncthreads();
  #pragma unroll
  for (int s = 1; s < 128; s <<= 1) {
    int t = (threadIdx.x >= s) ? buf[threadIdx.x - s] : 0;
    __syncthreads();
    buf[threadIdx.x] += t;
    __syncthreads();
  }
  if (threadIdx.x < NBLK) bsum[threadIdx.x] = buf[threadIdx.x];
}

__global__ void k_scanC(const int* __restrict__ deg, const int* __restrict__ part,
                        const int* __restrict__ bsum, int* __restrict__ rowptr,
                        float* __restrict__ inv) {
  int i = blockIdx.x * 256 + threadIdx.x;
  if (i >= N_NODES) return;
  int off = blockIdx.x ? bsum[blockIdx.x - 1] : 0;
  rowptr[i + 1] = off + part[i];
  if (i == 0) rowptr[0] = 0;
  inv[i] = 1.0f / (float)max(deg[i], 1);
}

__global__ void k_fill(const int* __restrict__ src, const int* __restrict__ dst,
                       int* __restrict__ cursor, int* __restrict__ col) {
  int e = blockIdx.x * blockDim.x + threadIdx.x;
  if (e >= N_EDGES) return;
  unsigned d = (unsigned)dst[e];
  if (d >= N_NODES) return;
  int p = atomicAdd(&cursor[d], 1);
  col[p] = src[e];
}

// ---------- weights -> bf16 pool ----------
__global__ void k_cvtw(const float* s0, const float* s1, const float* s2,
                       const float* s3, const float* s4, const float* s5,
                       const float* s6, const float* s7, const float* s8,
                       const float* s9, ushort* __restrict__ dst) {
  int t = blockIdx.x * blockDim.x + threadIdx.x;
  int e = t * 4;
  if (e >= 425984) return;
  const float* s; int off;
  if      (e < 16384)  { s = s0; off = e; }
  else if (e < 49152)  { s = s1; off = e - 16384; }
  else if (e < 81920)  { s = s2; off = e - 49152; }
  else if (e < 147456) { s = s3; off = e - 81920; }
  else if (e < 212992) { s = s4; off = e - 147456; }
  else if (e < 278528) { s = s5; off = e - 212992; }
  else if (e < 344064) { s = s6; off = e - 278528; }
  else if (e < 376832) { s = s7; off = e - 344064; }
  else if (e < 409600) { s = s8; off = e - 376832; }
  else                 { s = s9; off = e - 409600; }
  float4 v = *(const float4*)(s + off);
  dst[e + 0] = f2bf(v.x); dst[e + 1] = f2bf(v.y);
  dst[e + 2] = f2bf(v.z); dst[e + 3] = f2bf(v.w);
}

// ---------- gather-mean (bf16 in, fp32 acc, bf16 out): one wave per node ----------
template <int DIM>
__global__ __launch_bounds__(256) void k_gather(
    const ushort* __restrict__ z, const int* __restrict__ rowptr,
    const int* __restrict__ col, const float* __restrict__ inv,
    ushort* __restrict__ mean) {
  int node = blockIdx.x * 4 + (threadIdx.x >> 6);
  if (node >= N_NODES) return;
  int lane = threadIdx.x & 63;
  constexpr int V = DIM / 64;
  float acc[V] = {};
  int r0 = rowptr[node], r1 = rowptr[node + 1];
  #pragma unroll 2
  for (int j = r0; j < r1; ++j) {
    int s = col[j];
    const ushort* zp = z + (size_t)s * DIM + lane * V;
    if constexpr (V == 4) {
      ushort4 v = *(const ushort4*)zp;
      acc[0] += bf2f(v.x); acc[1] += bf2f(v.y);
      acc[2] += bf2f(v.z); acc[3] += bf2f(v.w);
    } else {
      ushort2 v = *(const ushort2*)zp;
      acc[0] += bf2f(v.x); acc[1] += bf2f(v.y);
    }
  }
  float iv = inv[node];
  ushort* mp = mean + (size_t)node * DIM + lane * V;
  #pragma unroll
  for (int k = 0; k < V; ++k) mp[k] = f2bf(acc[k] * iv);
}

// ======================= GEMM (LDS-staged W, swizzled) =======================
// Wt LDS layout: 64 rows (output cols) x DIN, row-major, byte XOR-swizzle
// addr ^= ((row&7)<<4)  (bits 4-6 only; never crosses a 256B/512B row).

template <int DIN>
__device__ __forceinline__ void stage_w(const ushort* __restrict__ Wsrc, char* Wt) {
  constexpr int LOGR = (DIN == 256) ? 9 : 8;       // log2(row bytes)
  const char* g = (const char*)Wsrc;
  #pragma unroll
  for (int i = 0; i < (64 * DIN * 2) / 4096; ++i) {
    int p = i * 4096 + threadIdx.x * 16;
    int row = p >> LOGR;
    bf16x8 v = *(const bf16x8*)(g + p);
    *(bf16x8*)(Wt + (p ^ ((row & 7) << 4))) = v;
  }
}

template <bool AF32, int DIN>
__device__ __forceinline__ void load_a(const void* __restrict__ A, int arow, int lb,
                                       bf16x8* af) {
  #pragma unroll
  for (int kk = 0; kk < DIN / 32; ++kk) {
    if constexpr (AF32) {
      const float* ap = (const float*)A + (size_t)arow * DIN + kk * 32 + lb * 8;
      float4 u = *(const float4*)ap;
      float4 v = *(const float4*)(ap + 4);
      bf16x8 a;
      a[0] = (short)f2bf(u.x); a[1] = (short)f2bf(u.y);
      a[2] = (short)f2bf(u.z); a[3] = (short)f2bf(u.w);
      a[4] = (short)f2bf(v.x); a[5] = (short)f2bf(v.y);
      a[6] = (short)f2bf(v.z); a[7] = (short)f2bf(v.w);
      af[kk] = a;
    } else {
      af[kk] = *(const bf16x8*)((const ushort*)A + (size_t)arow * DIN + kk * 32 + lb * 8);
    }
  }
}

template <int DIN>
__device__ __forceinline__ void compute(const bf16x8* af, const char* Wt,
                                        int la, int lb, f32x4* acc) {
  constexpr int LOGR = (DIN == 256) ? 9 : 8;
  #pragma unroll
  for (int kk = 0; kk < DIN / 32; ++kk) {
    #pragma unroll
    for (int nf = 0; nf < 4; ++nf) {
      int r = nf * 16 + la;
      int ad = (r << LOGR) + (kk * 32 + lb * 8) * 2;
      ad ^= ((r & 7) << 4);
      bf16x8 b = *(const bf16x8*)(Wt + ad);
      acc[nf] = __builtin_amdgcn_mfma_f32_16x16x32_bf16(af[kk], b, acc[nf], 0, 0, 0);
    }
  }
}

// grid (NPAD/64, DOUT/64); block 256 = 4 waves; block tile 64 rows x 64 cols.
template <bool AF32, bool CF32, int DIN, int DOUT, bool DUAL>
__global__ __launch_bounds__(256) void k_gemm(
    const void* __restrict__ A1v, const ushort* __restrict__ W1,
    const void* __restrict__ A2v, const ushort* __restrict__ W2,
    const float* __restrict__ bias, void* __restrict__ Cv, int Mstore)
{
  __shared__ __align__(16) char Wt[64 * DIN * 2];
  int lane = threadIdx.x & 63, wid = threadIdx.x >> 6;
  int la = lane & 15, lb = lane >> 4;
  int rowBase = blockIdx.x * 64 + wid * 16;
  int colBase = blockIdx.y * 64;
  int arow = rowBase + la; if (arow >= N_NODES) arow = N_NODES - 1;

  f32x4 acc[4];
  #pragma unroll
  for (int i = 0; i < 4; ++i) acc[i] = {0.f, 0.f, 0.f, 0.f};

  bf16x8 af[DIN / 32];
  load_a<AF32, DIN>(A1v, arow, lb, af);            // A frags in flight first
  stage_w<DIN>(W1 + (size_t)colBase * DIN, Wt);
  __syncthreads();
  compute<DIN>(af, Wt, la, lb, acc);

  if constexpr (DUAL) {
    __syncthreads();                               // all waves done reading Wt
    load_a<false, DIN>(A2v, arow, lb, af);
    stage_w<DIN>(W2 + (size_t)colBase * DIN, Wt);
    __syncthreads();
    compute<DIN>(af, Wt, la, lb, acc);
  }

  // C/D layout: col = lane&15, row = (lane>>4)*4 + reg
  #pragma unroll
  for (int nf = 0; nf < 4; ++nf) {
    int col = colBase + nf * 16 + la;
    float bv = bias ? bias[col] : 0.0f;
    #pragma unroll
    for (int i = 0; i < 4; ++i) {
      int row = rowBase + lb * 4 + i;
      if (row < Mstore) {
        float o = acc[nf][i] + bv;
        if constexpr (CF32) ((float*)Cv)[(size_t)row * DOUT + col] = o;
        else                ((ushort*)Cv)[(size_t)row * DOUT + col] = f2bf(o);
      }
    }
  }
}

// ---------- BN stats (dim 256, bf16, vectorized row-major reads) ----------
__global__ __launch_bounds__(256) void k_stats(const ushort* __restrict__ h,
                                               float* __restrict__ stats,
                                               int rowsPerBlock) {
  __shared__ float sb[256], qb[256];
  sb[threadIdx.x] = 0.f; qb[threadIdx.x] = 0.f;
  __syncthreads();
  int rg = threadIdx.x >> 5;          // 8 row groups
  int g  = threadIdx.x & 31;          // col group: cols g*8 .. g*8+7
  int r0 = blockIdx.x * rowsPerBlock;
  int r1 = r0 + rowsPerBlock; if (r1 > N_NODES) r1 = N_NODES;
  float s[8] = {}, q[8] = {};
  for (int r = r0 + rg; r < r1; r += 8) {
    bf16x8 v = *(const bf16x8*)(h + (size_t)r * 256 + g * 8);
    #pragma unroll
    for (int j = 0; j < 8; ++j) { float f = bf2f((ushort)v[j]); s[j] += f; q[j] += f * f; }
  }
  #pragma unroll
  for (int j = 0; j < 8; ++j) {
    atomicAdd(&sb[g * 8 + j], s[j]);
    atomicAdd(&qb[g * 8 + j], q[j]);
  }
  __syncthreads();
  atomicAdd(&stats[threadIdx.x], sb[threadIdx.x]);
  atomicAdd(&stats[256 + threadIdx.x], qb[threadIdx.x]);
}

__global__ void k_bnprep(const float* __restrict__ stats, const float* __restrict__ gamma,
                         const float* __restrict__ beta, float* __restrict__ bnp) {
  int c = threadIdx.x;
  float m = stats[c] * (1.0f / N_NODES);
  float var = stats[256 + c] * (1.0f / N_NODES) - m * m;
  float rs = rsqrtf(var + BN_EPS);
  float sc = rs * gamma[c];
  bnp[c] = sc;
  bnp[256 + c] = beta[c] - m * sc;
}

__global__ void k_bnrelu(ushort* __restrict__ h, const float* __restrict__ bnp) {
  int t = blockIdx.x * blockDim.x + threadIdx.x;
  int i = t >> 5;
  if (i >= N_NODES) return;
  int g = t & 31;
  ushort* p = h + (size_t)i * 256 + g * 8;
  bf16x8 v = *(bf16x8*)p;
  #pragma unroll
  for (int j = 0; j < 8; ++j) {
    int c = g * 8 + j;
    float f = bf2f((ushort)v[j]) * bnp[c] + bnp[256 + c];
    v[j] = (short)f2bf(fmaxf(f, 0.0f));
  }
  *(bf16x8*)p = v;
}

extern "C" void kernel_launch(void* const* d_in, const int* in_sizes, int n_in,
                              void* d_out, int out_size, void* d_ws, size_t ws_size,
                              hipStream_t stream) {
  const float* x    = (const float*)d_in[0];
  const int*   ei   = (const int*)d_in[1];
  const float* encW = (const float*)d_in[2];
  const float* encb = (const float*)d_in[3];
  const float* Wl0  = (const float*)d_in[4];
  const float* bl0  = (const float*)d_in[5];
  const float* Wr0  = (const float*)d_in[6];
  const float* Wl1  = (const float*)d_in[7];
  const float* bl1  = (const float*)d_in[8];
  const float* Wr1  = (const float*)d_in[9];
  const float* Wl2  = (const float*)d_in[10];
  const float* bl2  = (const float*)d_in[11];
  const float* Wr2  = (const float*)d_in[12];
  const float* Wl3  = (const float*)d_in[13];
  const float* bl3  = (const float*)d_in[14];
  const float* Wr3  = (const float*)d_in[15];
  const float* g0   = (const float*)d_in[16];
  const float* b0   = (const float*)d_in[17];
  const float* g1   = (const float*)d_in[18];
  const float* b1   = (const float*)d_in[19];
  const float* g2   = (const float*)d_in[20];
  const float* b2   = (const float*)d_in[21];
  const float* decW = (const float*)d_in[22];
  const float* decb = (const float*)d_in[23];

  const int* src = ei;
  const int* dst = ei + N_EDGES;

  char* ws = (char*)d_ws;
  size_t off = 0;
  auto alloc = [&](size_t bytes) { char* p = ws + off; off += (bytes + 255) & ~255ull; return p; };
  ushort* bufA   = (ushort*)alloc((size_t)NPAD * 256 * 2);
  ushort* bufB   = (ushort*)alloc((size_t)NPAD * 256 * 2);
  ushort* mean   = (ushort*)alloc((size_t)NPAD * 256 * 2);
  int*    deg    = (int*)   alloc((size_t)N_NODES * 4);
  int*    part   = (int*)   alloc((size_t)N_NODES * 4);
  int*    bsum   = (int*)   alloc(128 * 4);
  int*    rowptr = (int*)   alloc((size_t)(N_NODES + 1) * 4);
  int*    cursor = (int*)   alloc((size_t)N_NODES * 4);
  int*    colidx = (int*)   alloc((size_t)N_EDGES * 4);
  float*  inv    = (float*) alloc((size_t)N_NODES * 4);
  float*  stats  = (float*) alloc(512 * 4);
  float*  bnp    = (float*) alloc(512 * 4);
  ushort* wpool  = (ushort*)alloc(425984 * 2);

  const ushort* wEnc = wpool;
  const ushort* wL0  = wpool + 16384;
  const ushort* wR0  = wpool + 49152;
  const ushort* wL1  = wpool + 81920;
  const ushort* wR1  = wpool + 147456;
  const ushort* wL2  = wpool + 212992;
  const ushort* wR2  = wpool + 278528;
  const ushort* wL3  = wpool + 344064;
  const ushort* wR3  = wpool + 376832;
  const ushort* wDec = wpool + 409600;

  // ---- CSR build (once; reused by all 4 layers) ----
  hipMemsetAsync(deg, 0, (size_t)N_NODES * 4, stream);
  k_deg<<<(N_EDGES + 255) / 256, 256, 0, stream>>>(dst, deg);
  k_scanA<<<NBLK, 256, 0, stream>>>(deg, part, bsum);
  k_scanB<<<1, 128, 0, stream>>>(bsum);
  k_scanC<<<NBLK, 256, 0, stream>>>(deg, part, bsum, rowptr, inv);
  hipMemcpyAsync(cursor, rowptr, (size_t)N_NODES * 4, hipMemcpyDeviceToDevice, stream);
  k_fill<<<(N_EDGES + 255) / 256, 256, 0, stream>>>(src, dst, cursor, colidx);

  k_cvtw<<<(106496 + 255) / 256, 256, 0, stream>>>(encW, Wl0, Wr0, Wl1, Wr1, Wl2, Wr2,
                                                   Wl3, Wr3, decW, wpool);

  const int GGRID = NPAD / 64;   // 313

  // encoder: bufA = x @ encW^T + encb  (f32 A, bf16 C)
  k_gemm<true, false, 128, 128, false><<<dim3(GGRID, 2), 256, 0, stream>>>(
      x, wEnc, nullptr, nullptr, encb, bufA, N_NODES);

  auto bnrelu = [&](ushort* h, const float* ga, const float* be) {
    hipMemsetAsync(stats, 0, 512 * 4, stream);
    k_stats<<<100, 256, 0, stream>>>(h, stats, 200);
    k_bnprep<<<1, 256, 0, stream>>>(stats, ga, be, bnp);
    int total = N_NODES * 32;
    k_bnrelu<<<(total + 255) / 256, 256, 0, stream>>>(h, bnp);
  };

  // SAGE 0: din 128 -> dout 256
  k_gather<128><<<(N_NODES + 3) / 4, 256, 0, stream>>>(bufA, rowptr, colidx, inv, mean);
  k_gemm<false, false, 128, 256, true><<<dim3(GGRID, 4), 256, 0, stream>>>(
      mean, wL0, bufA, wR0, bl0, bufB, N_NODES);
  bnrelu(bufB, g0, b0);

  // SAGE 1: 256 -> 256
  k_gather<256><<<(N_NODES + 3) / 4, 256, 0, stream>>>(bufB, rowptr, colidx, inv, mean);
  k_gemm<false, false, 256, 256, true><<<dim3(GGRID, 4), 256, 0, stream>>>(
      mean, wL1, bufB, wR1, bl1, bufA, N_NODES);
  bnrelu(bufA, g1, b1);

  // SAGE 2: 256 -> 256
  k_gather<256><<<(N_NODES + 3) / 4, 256, 0, stream>>>(bufA, rowptr, colidx, inv, mean);
  k_gemm<false, false, 256, 256, true><<<dim3(GGRID, 4), 256, 0, stream>>>(
      mean, wL2, bufA, wR2, bl2, bufB, N_NODES);
  bnrelu(bufB, g2, b2);

  // SAGE 3: 256 -> 128 (no BN/ReLU)
  k_gather<256><<<(N_NODES + 3) / 4, 256, 0, stream>>>(bufB, rowptr, colidx, inv, mean);
  k_gemm<false, false, 256, 128, true><<<dim3(GGRID, 2), 256, 0, stream>>>(
      mean, wL3, bufB, wR3, bl3, bufA, N_NODES);

  // decoder: d_out = bufA @ decW^T + decb  (bf16 A, f32 C)
  k_gemm<false, true, 128, 128, false><<<dim3(GGRID, 2), 256, 0, stream>>>(
      bufA, wDec, nullptr, nullptr, decb, (float*)d_out, N_NODES);
}

// Round 8
// 305.085 us; speedup vs baseline: 1.8808x; 1.0442x over previous
//
#include <hip/hip_runtime.h>

#define N_NODES 20000
#define N_EDGES 320000
#define NPAD    20032
#define BN_EPS  1e-5f
#define NBLK    79          // ceil(20000/256)

using bf16x8 = __attribute__((ext_vector_type(8))) short;
using f32x4  = __attribute__((ext_vector_type(4))) float;

__device__ __forceinline__ float bf2f(ushort u) {
  union { unsigned i; float f; } t; t.i = ((unsigned)u) << 16; return t.f;
}
__device__ __forceinline__ ushort f2bf(float f) {
  unsigned x = __float_as_uint(f);
  return (ushort)((x + 0x7fffu + ((x >> 16) & 1u)) >> 16);   // RNE
}

// ---------- CSR build ----------
__global__ void k_deg(const int* __restrict__ dst, int* __restrict__ deg) {
  int t = blockIdx.x * blockDim.x + threadIdx.x;
  if (t < N_EDGES) { unsigned d = (unsigned)dst[t]; if (d < N_NODES) atomicAdd(&deg[d], 1); }
}

__global__ void k_scanA(const int* __restrict__ deg, int* __restrict__ part,
                        int* __restrict__ bsum) {
  __shared__ int buf[256];
  int i = blockIdx.x * 256 + threadIdx.x;
  int v = (i < N_NODES) ? deg[i] : 0;
  buf[threadIdx.x] = v;
  __syncthreads();
  #pragma unroll
  for (int s = 1; s < 256; s <<= 1) {
    int t = (threadIdx.x >= s) ? buf[threadIdx.x - s] : 0;
    __syncthreads();
    buf[threadIdx.x] += t;
    __syncthreads();
  }
  if (i < N_NODES) part[i] = buf[threadIdx.x];
  if (threadIdx.x == 255) bsum[blockIdx.x] = buf[255];
}

__global__ void k_scanB(int* __restrict__ bsum) {
  __shared__ int buf[128];
  int v = (threadIdx.x < NBLK) ? bsum[threadIdx.x] : 0;
  buf[threadIdx.x] = v;
  __syncthreads();
  #pragma unroll
  for (int s = 1; s < 128; s <<= 1) {
    int t = (threadIdx.x >= s) ? buf[threadIdx.x - s] : 0;
    __syncthreads();
    buf[threadIdx.x] += t;
    __syncthreads();
  }
  if (threadIdx.x < NBLK) bsum[threadIdx.x] = buf[threadIdx.x];
}

__global__ void k_scanC(const int* __restrict__ deg, const int* __restrict__ part,
                        const int* __restrict__ bsum, int* __restrict__ rowptr,
                        float* __restrict__ inv) {
  int i = blockIdx.x * 256 + threadIdx.x;
  if (i >= N_NODES) return;
  int off = blockIdx.x ? bsum[blockIdx.x - 1] : 0;
  rowptr[i + 1] = off + part[i];
  if (i == 0) rowptr[0] = 0;
  inv[i] = 1.0f / (float)max(deg[i], 1);
}

__global__ void k_fill(const int* __restrict__ src, const int* __restrict__ dst,
                       int* __restrict__ cursor, int* __restrict__ col) {
  int e = blockIdx.x * blockDim.x + threadIdx.x;
  if (e >= N_EDGES) return;
  unsigned d = (unsigned)dst[e];
  if (d >= N_NODES) return;
  int p = atomicAdd(&cursor[d], 1);
  col[p] = src[e];
}

// ---------- weights -> bf16 pool ----------
__global__ void k_cvtw(const float* s0, const float* s1, const float* s2,
                       const float* s3, const float* s4, const float* s5,
                       const float* s6, const float* s7, const float* s8,
                       const float* s9, ushort* __restrict__ dst) {
  int t = blockIdx.x * blockDim.x + threadIdx.x;
  int e = t * 4;
  if (e >= 425984) return;
  const float* s; int off;
  if      (e < 16384)  { s = s0; off = e; }
  else if (e < 49152)  { s = s1; off = e - 16384; }
  else if (e < 81920)  { s = s2; off = e - 49152; }
  else if (e < 147456) { s = s3; off = e - 81920; }
  else if (e < 212992) { s = s4; off = e - 147456; }
  else if (e < 278528) { s = s5; off = e - 212992; }
  else if (e < 344064) { s = s6; off = e - 278528; }
  else if (e < 376832) { s = s7; off = e - 344064; }
  else if (e < 409600) { s = s8; off = e - 376832; }
  else                 { s = s9; off = e - 409600; }
  float4 v = *(const float4*)(s + off);
  dst[e + 0] = f2bf(v.x); dst[e + 1] = f2bf(v.y);
  dst[e + 2] = f2bf(v.z); dst[e + 3] = f2bf(v.w);
}

// ---------- gather-mean, optional on-the-fly BN+ReLU of source rows ----------
template <int DIM, bool BN>
__global__ __launch_bounds__(256) void k_gather(
    const ushort* __restrict__ z, const int* __restrict__ rowptr,
    const int* __restrict__ col, const float* __restrict__ inv,
    const float* __restrict__ bnp, ushort* __restrict__ mean) {
  int node = blockIdx.x * 4 + (threadIdx.x >> 6);
  if (node >= N_NODES) return;
  int lane = threadIdx.x & 63;
  constexpr int V = DIM / 64;
  float sc[V], sh[V];
  if constexpr (BN) {
    #pragma unroll
    for (int k = 0; k < V; ++k) { sc[k] = bnp[lane * V + k]; sh[k] = bnp[256 + lane * V + k]; }
  }
  float acc[V] = {};
  int r0 = rowptr[node], r1 = rowptr[node + 1];
  #pragma unroll 2
  for (int j = r0; j < r1; ++j) {
    int s = col[j];
    const ushort* zp = z + (size_t)s * DIM + lane * V;
    if constexpr (V == 4) {
      ushort4 v = *(const ushort4*)zp;
      float f0 = bf2f(v.x), f1 = bf2f(v.y), f2 = bf2f(v.z), f3 = bf2f(v.w);
      if constexpr (BN) {
        f0 = fmaxf(f0 * sc[0] + sh[0], 0.f); f1 = fmaxf(f1 * sc[1] + sh[1], 0.f);
        f2 = fmaxf(f2 * sc[2] + sh[2], 0.f); f3 = fmaxf(f3 * sc[3] + sh[3], 0.f);
      }
      acc[0] += f0; acc[1] += f1; acc[2] += f2; acc[3] += f3;
    } else {
      ushort2 v = *(const ushort2*)zp;
      float f0 = bf2f(v.x), f1 = bf2f(v.y);
      if constexpr (BN) {
        f0 = fmaxf(f0 * sc[0] + sh[0], 0.f); f1 = fmaxf(f1 * sc[1] + sh[1], 0.f);
      }
      acc[0] += f0; acc[1] += f1;
    }
  }
  float iv = inv[node];
  ushort* mp = mean + (size_t)node * DIM + lane * V;
  #pragma unroll
  for (int k = 0; k < V; ++k) mp[k] = f2bf(acc[k] * iv);
}

// ======================= GEMM (LDS-staged W, swizzled) =======================
template <int DIN>
__device__ __forceinline__ void stage_w(const ushort* __restrict__ Wsrc, char* Wt) {
  constexpr int LOGR = (DIN == 256) ? 9 : 8;
  const char* g = (const char*)Wsrc;
  #pragma unroll
  for (int i = 0; i < (64 * DIN * 2) / 4096; ++i) {
    int p = i * 4096 + threadIdx.x * 16;
    int row = p >> LOGR;
    bf16x8 v = *(const bf16x8*)(g + p);
    *(bf16x8*)(Wt + (p ^ ((row & 7) << 4))) = v;
  }
}

// A-fragment load; optional f32 source, optional on-the-fly BN+ReLU (bf16 only)
template <bool AF32, bool BN, int DIN>
__device__ __forceinline__ void load_a(const void* __restrict__ A,
                                       const float* __restrict__ bnp,
                                       int arow, int lb, bf16x8* af) {
  #pragma unroll
  for (int kk = 0; kk < DIN / 32; ++kk) {
    if constexpr (AF32) {
      const float* ap = (const float*)A + (size_t)arow * DIN + kk * 32 + lb * 8;
      float4 u = *(const float4*)ap;
      float4 v = *(const float4*)(ap + 4);
      bf16x8 a;
      a[0] = (short)f2bf(u.x); a[1] = (short)f2bf(u.y);
      a[2] = (short)f2bf(u.z); a[3] = (short)f2bf(u.w);
      a[4] = (short)f2bf(v.x); a[5] = (short)f2bf(v.y);
      a[6] = (short)f2bf(v.z); a[7] = (short)f2bf(v.w);
      af[kk] = a;
    } else {
      bf16x8 r = *(const bf16x8*)((const ushort*)A + (size_t)arow * DIN + kk * 32 + lb * 8);
      if constexpr (BN) {
        int c0 = kk * 32 + lb * 8;
        float4 s0 = *(const float4*)(bnp + c0);
        float4 s1 = *(const float4*)(bnp + c0 + 4);
        float4 h0 = *(const float4*)(bnp + 256 + c0);
        float4 h1 = *(const float4*)(bnp + 256 + c0 + 4);
        r[0] = (short)f2bf(fmaxf(bf2f((ushort)r[0]) * s0.x + h0.x, 0.f));
        r[1] = (short)f2bf(fmaxf(bf2f((ushort)r[1]) * s0.y + h0.y, 0.f));
        r[2] = (short)f2bf(fmaxf(bf2f((ushort)r[2]) * s0.z + h0.z, 0.f));
        r[3] = (short)f2bf(fmaxf(bf2f((ushort)r[3]) * s0.w + h0.w, 0.f));
        r[4] = (short)f2bf(fmaxf(bf2f((ushort)r[4]) * s1.x + h1.x, 0.f));
        r[5] = (short)f2bf(fmaxf(bf2f((ushort)r[5]) * s1.y + h1.y, 0.f));
        r[6] = (short)f2bf(fmaxf(bf2f((ushort)r[6]) * s1.z + h1.z, 0.f));
        r[7] = (short)f2bf(fmaxf(bf2f((ushort)r[7]) * s1.w + h1.w, 0.f));
      }
      af[kk] = r;
    }
  }
}

template <int DIN>
__device__ __forceinline__ void compute(const bf16x8* af, const char* Wt,
                                        int la, int lb, f32x4* acc) {
  constexpr int LOGR = (DIN == 256) ? 9 : 8;
  #pragma unroll
  for (int kk = 0; kk < DIN / 32; ++kk) {
    #pragma unroll
    for (int nf = 0; nf < 4; ++nf) {
      int r = nf * 16 + la;
      int ad = (r << LOGR) + (kk * 32 + lb * 8) * 2;
      ad ^= ((r & 7) << 4);
      bf16x8 b = *(const bf16x8*)(Wt + ad);
      acc[nf] = __builtin_amdgcn_mfma_f32_16x16x32_bf16(af[kk], b, acc[nf], 0, 0, 0);
    }
  }
}

// grid (NPAD/64, DOUT/64); block 256 = 4 waves; tile 64 rows x 64 cols.
// STATS: accumulate per-column sum/sumsq of (acc+bias) into stats[512] via atomics.
// BNA2: apply bnp affine+relu to A2 loads.
template <bool AF32, bool CF32, int DIN, int DOUT, bool DUAL, bool BNA2, bool STATS>
__global__ __launch_bounds__(256) void k_gemm(
    const void* __restrict__ A1v, const ushort* __restrict__ W1,
    const void* __restrict__ A2v, const ushort* __restrict__ W2,
    const float* __restrict__ bias, const float* __restrict__ bnp,
    float* __restrict__ stats, void* __restrict__ Cv, int Mstore)
{
  __shared__ __align__(16) char Wt[64 * DIN * 2];
  __shared__ float sbuf[64], qbuf[64];
  int lane = threadIdx.x & 63, wid = threadIdx.x >> 6;
  int la = lane & 15, lb = lane >> 4;
  int rowBase = blockIdx.x * 64 + wid * 16;
  int colBase = blockIdx.y * 64;
  int arow = rowBase + la; if (arow >= N_NODES) arow = N_NODES - 1;

  if constexpr (STATS) {
    if (threadIdx.x < 64) { sbuf[threadIdx.x] = 0.f; qbuf[threadIdx.x] = 0.f; }
  }

  f32x4 acc[4];
  #pragma unroll
  for (int i = 0; i < 4; ++i) acc[i] = {0.f, 0.f, 0.f, 0.f};

  bf16x8 af[DIN / 32];
  load_a<AF32, false, DIN>(A1v, nullptr, arow, lb, af);
  stage_w<DIN>(W1 + (size_t)colBase * DIN, Wt);
  __syncthreads();
  compute<DIN>(af, Wt, la, lb, acc);

  if constexpr (DUAL) {
    __syncthreads();
    load_a<false, BNA2, DIN>(A2v, bnp, arow, lb, af);
    stage_w<DIN>(W2 + (size_t)colBase * DIN, Wt);
    __syncthreads();
    compute<DIN>(af, Wt, la, lb, acc);
  }

  // C/D layout: col = lane&15, row = (lane>>4)*4 + reg
  float colsum[4] = {}, colsq[4] = {};
  #pragma unroll
  for (int nf = 0; nf < 4; ++nf) {
    int col = colBase + nf * 16 + la;
    float bv = bias ? bias[col] : 0.0f;
    #pragma unroll
    for (int i = 0; i < 4; ++i) {
      int row = rowBase + lb * 4 + i;
      float o = acc[nf][i] + bv;
      if (row < Mstore) {
        if constexpr (CF32) ((float*)Cv)[(size_t)row * DOUT + col] = o;
        else                ((ushort*)Cv)[(size_t)row * DOUT + col] = f2bf(o);
      }
      if constexpr (STATS) {
        if (row < N_NODES) { colsum[nf] += o; colsq[nf] += o * o; }
      }
    }
  }

  if constexpr (STATS) {
    #pragma unroll
    for (int nf = 0; nf < 4; ++nf) {
      float sv = colsum[nf], qv = colsq[nf];
      sv += __shfl_xor(sv, 16); qv += __shfl_xor(qv, 16);
      sv += __shfl_xor(sv, 32); qv += __shfl_xor(qv, 32);
      if (lb == 0) { atomicAdd(&sbuf[nf * 16 + la], sv); atomicAdd(&qbuf[nf * 16 + la], qv); }
    }
    __syncthreads();
    if (threadIdx.x < 64)        atomicAdd(&stats[colBase + threadIdx.x], sbuf[threadIdx.x]);
    else if (threadIdx.x < 128)  atomicAdd(&stats[256 + colBase + threadIdx.x - 64], qbuf[threadIdx.x - 64]);
  }
}

// ---------- per-column BN scale/shift ----------
__global__ void k_bnprep(const float* __restrict__ stats, const float* __restrict__ gamma,
                         const float* __restrict__ beta, float* __restrict__ bnp) {
  int c = threadIdx.x;
  float m = stats[c] * (1.0f / N_NODES);
  float var = stats[256 + c] * (1.0f / N_NODES) - m * m;
  float rs = rsqrtf(var + BN_EPS);
  float sc = rs * gamma[c];
  bnp[c] = sc;
  bnp[256 + c] = beta[c] - m * sc;
}

extern "C" void kernel_launch(void* const* d_in, const int* in_sizes, int n_in,
                              void* d_out, int out_size, void* d_ws, size_t ws_size,
                              hipStream_t stream) {
  const float* x    = (const float*)d_in[0];
  const int*   ei   = (const int*)d_in[1];
  const float* encW = (const float*)d_in[2];
  const float* encb = (const float*)d_in[3];
  const float* Wl0  = (const float*)d_in[4];
  const float* bl0  = (const float*)d_in[5];
  const float* Wr0  = (const float*)d_in[6];
  const float* Wl1  = (const float*)d_in[7];
  const float* bl1  = (const float*)d_in[8];
  const float* Wr1  = (const float*)d_in[9];
  const float* Wl2  = (const float*)d_in[10];
  const float* bl2  = (const float*)d_in[11];
  const float* Wr2  = (const float*)d_in[12];
  const float* Wl3  = (const float*)d_in[13];
  const float* bl3  = (const float*)d_in[14];
  const float* Wr3  = (const float*)d_in[15];
  const float* g0   = (const float*)d_in[16];
  const float* b0   = (const float*)d_in[17];
  const float* g1   = (const float*)d_in[18];
  const float* b1   = (const float*)d_in[19];
  const float* g2   = (const float*)d_in[20];
  const float* b2   = (const float*)d_in[21];
  const float* decW = (const float*)d_in[22];
  const float* decb = (const float*)d_in[23];

  const int* src = ei;
  const int* dst = ei + N_EDGES;

  char* ws = (char*)d_ws;
  size_t off = 0;
  auto alloc = [&](size_t bytes) { char* p = ws + off; off += (bytes + 255) & ~255ull; return p; };
  ushort* bufA   = (ushort*)alloc((size_t)NPAD * 256 * 2);
  ushort* bufB   = (ushort*)alloc((size_t)NPAD * 256 * 2);
  ushort* mean   = (ushort*)alloc((size_t)NPAD * 256 * 2);
  int*    deg    = (int*)   alloc((size_t)N_NODES * 4);
  int*    part   = (int*)   alloc((size_t)N_NODES * 4);
  int*    bsum   = (int*)   alloc(128 * 4);
  int*    rowptr = (int*)   alloc((size_t)(N_NODES + 1) * 4);
  int*    cursor = (int*)   alloc((size_t)N_NODES * 4);
  int*    colidx = (int*)   alloc((size_t)N_EDGES * 4);
  float*  inv    = (float*) alloc((size_t)N_NODES * 4);
  float*  stats  = (float*) alloc(3 * 512 * 4);     // stats0|stats1|stats2
  float*  bnp    = (float*) alloc(3 * 512 * 4);     // bnp0|bnp1|bnp2
  ushort* wpool  = (ushort*)alloc(425984 * 2);

  float* stats0 = stats, *stats1 = stats + 512, *stats2 = stats + 1024;
  float* bnp0 = bnp, *bnp1 = bnp + 512, *bnp2 = bnp + 1024;

  const ushort* wEnc = wpool;
  const ushort* wL0  = wpool + 16384;
  const ushort* wR0  = wpool + 49152;
  const ushort* wL1  = wpool + 81920;
  const ushort* wR1  = wpool + 147456;
  const ushort* wL2  = wpool + 212992;
  const ushort* wR2  = wpool + 278528;
  const ushort* wL3  = wpool + 344064;
  const ushort* wR3  = wpool + 376832;
  const ushort* wDec = wpool + 409600;

  // ---- CSR build (once; reused by all 4 layers) ----
  hipMemsetAsync(deg, 0, (size_t)N_NODES * 4, stream);
  hipMemsetAsync(stats, 0, 3 * 512 * 4, stream);
  k_deg<<<(N_EDGES + 255) / 256, 256, 0, stream>>>(dst, deg);
  k_scanA<<<NBLK, 256, 0, stream>>>(deg, part, bsum);
  k_scanB<<<1, 128, 0, stream>>>(bsum);
  k_scanC<<<NBLK, 256, 0, stream>>>(deg, part, bsum, rowptr, inv);
  hipMemcpyAsync(cursor, rowptr, (size_t)N_NODES * 4, hipMemcpyDeviceToDevice, stream);
  k_fill<<<(N_EDGES + 255) / 256, 256, 0, stream>>>(src, dst, cursor, colidx);

  k_cvtw<<<(106496 + 255) / 256, 256, 0, stream>>>(encW, Wl0, Wr0, Wl1, Wr1, Wl2, Wr2,
                                                   Wl3, Wr3, decW, wpool);

  const int GGRID = NPAD / 64;   // 313
  const int NGB = (N_NODES + 3) / 4;

  // encoder: e(bufA) = x @ encW^T + encb  (f32 A, bf16 C)
  k_gemm<true, false, 128, 128, false, false, false><<<dim3(GGRID, 2), 256, 0, stream>>>(
      x, wEnc, nullptr, nullptr, encb, nullptr, nullptr, bufA, N_NODES);

  // SAGE0: h0(bufB) = mean(e)@Wl0 + bl0 + e@Wr0 ; stats0
  k_gather<128, false><<<NGB, 256, 0, stream>>>(bufA, rowptr, colidx, inv, nullptr, mean);
  k_gemm<false, false, 128, 256, true, false, true><<<dim3(GGRID, 4), 256, 0, stream>>>(
      mean, wL0, bufA, wR0, bl0, nullptr, stats0, bufB, N_NODES);
  k_bnprep<<<1, 256, 0, stream>>>(stats0, g0, b0, bnp0);

  // SAGE1: z1 = BN0(h0); h1(bufA) = mean(z1)@Wl1 + bl1 + z1@Wr1 ; stats1
  k_gather<256, true><<<NGB, 256, 0, stream>>>(bufB, rowptr, colidx, inv, bnp0, mean);
  k_gemm<false, false, 256, 256, true, true, true><<<dim3(GGRID, 4), 256, 0, stream>>>(
      mean, wL1, bufB, wR1, bl1, bnp0, stats1, bufA, N_NODES);
  k_bnprep<<<1, 256, 0, stream>>>(stats1, g1, b1, bnp1);

  // SAGE2: h2(bufB)
  k_gather<256, true><<<NGB, 256, 0, stream>>>(bufA, rowptr, colidx, inv, bnp1, mean);
  k_gemm<false, false, 256, 256, true, true, true><<<dim3(GGRID, 4), 256, 0, stream>>>(
      mean, wL2, bufA, wR2, bl2, bnp1, stats2, bufB, N_NODES);
  k_bnprep<<<1, 256, 0, stream>>>(stats2, g2, b2, bnp2);

  // SAGE3: o3(bufA) = mean(z3)@Wl3 + bl3 + z3@Wr3  (no BN after)
  k_gather<256, true><<<NGB, 256, 0, stream>>>(bufB, rowptr, colidx, inv, bnp2, mean);
  k_gemm<false, false, 256, 128, true, true, false><<<dim3(GGRID, 2), 256, 0, stream>>>(
      mean, wL3, bufB, wR3, bl3, bnp2, nullptr, bufA, N_NODES);

  // decoder: d_out = o3 @ decW^T + decb  (bf16 A, f32 C)
  k_gemm<false, true, 128, 128, false, false, false><<<dim3(GGRID, 2), 256, 0, stream>>>(
      bufA, wDec, nullptr, nullptr, decb, nullptr, nullptr, (float*)d_out, N_NODES);
}